// Round 3
// baseline (23967.883 us; speedup 1.0000x reference)
//
#include <hip/hip_runtime.h>
#include <hip/hip_bf16.h>

#define KD 128
#define HDD 512
#define BB 64
#define NE 512
#define NC 3584  // 7*HDD

// d_out element offsets (fp32 outputs concatenated flat in return order)
#define LAMB_OFF  0UL
#define CLOW_OFF  4194304UL    // B*N*K
#define CBAR_OFF  20971520UL   // + B*N*HD
#define DELTA_OFF 37748736UL
#define OGATE_OFF 54525952UL

__device__ __forceinline__ float sigf(float x) { return 1.0f / (1.0f + expf(-x)); }

// ---------------- pre-pass kernels ----------------

// one block per (b,t) row; write transposed marks_t[t][b]
__global__ void marks_k(const float* __restrict__ seq, int* __restrict__ marks_t) {
    int row = blockIdx.x;       // b*NE + t
    int k = threadIdx.x;        // 0..127
    int b = row / NE, t = row % NE;
    float v = seq[(size_t)row * KD + k];
    if (v > 0.5f) marks_t[t * BB + b] = k;
}

// tiled transpose: dst[c*R + r] = src[r*C + c]
__global__ void transpose_k(const float* __restrict__ src, float* __restrict__ dst,
                            int R, int C) {
    __shared__ float tile[32][33];
    int tx = threadIdx.x & 31, ty = threadIdx.x >> 5;   // 256 threads: 32x8
    int c0 = blockIdx.x * 32, r0 = blockIdx.y * 32;
    for (int i = ty; i < 32; i += 8) {
        int r = r0 + i, c = c0 + tx;
        if (r < R && c < C) tile[i][tx] = src[(size_t)r * C + c];
    }
    __syncthreads();
    for (int i = ty; i < 32; i += 8) {
        int c = c0 + i, r = r0 + tx;
        if (r < R && c < C) dst[(size_t)c * R + r] = tile[tx][i];
    }
}

// ---------------- grid barrier (sense-reversing, agent scope) ----------------

__device__ __forceinline__ void grid_barrier(unsigned* cnt, unsigned* gen, int nblocks) {
    __syncthreads();                     // all waves drain vmem (compiler emits vmcnt(0))
    if (threadIdx.x == 0) {
        __threadfence();                 // release: write back dirty L2 (cross-XCD visibility)
        unsigned g = __hip_atomic_load(gen, __ATOMIC_RELAXED, __HIP_MEMORY_SCOPE_AGENT);
        unsigned a = __hip_atomic_fetch_add(cnt, 1u, __ATOMIC_ACQ_REL, __HIP_MEMORY_SCOPE_AGENT);
        if (a == (unsigned)(nblocks - 1)) {
            __hip_atomic_store(cnt, 0u, __ATOMIC_RELAXED, __HIP_MEMORY_SCOPE_AGENT);
            __hip_atomic_store(gen, g + 1u, __ATOMIC_RELEASE, __HIP_MEMORY_SCOPE_AGENT);
        } else {
            while (__hip_atomic_load(gen, __ATOMIC_RELAXED, __HIP_MEMORY_SCOPE_AGENT) == g) {
                __builtin_amdgcn_s_sleep(2);
            }
        }
        __threadfence();                 // acquire: invalidate stale L1/L2 before reading remote h
    }
    __syncthreads();
}

// ---------------- persistent scan kernel ----------------
// 256 blocks x 256 threads, 1 block/CU (LDS-capped). Block wg owns j = {2wg, 2wg+1}.
// wave 0: gates 0..3, j0   wave 1: gates 0..3, j1
// wave 2: gates 4..6 + (lamb row wg if wg<128), j0   wave 3: gates 4..6 + dup, j1
__global__ void __launch_bounds__(256, 1) ctlstm_persist(
    const float* __restrict__ Wvt,     // [3584][512]
    const float* __restrict__ Wut,     // [3584][128]
    const float* __restrict__ Wlt,     // [128][512]
    const float* __restrict__ bU, const float* __restrict__ bV,
    const float* __restrict__ blamb, const float* __restrict__ scale,
    const float* __restrict__ times_t, // [513][64]
    const int* __restrict__ marks_t,   // [512][64]
    float* __restrict__ hg0, float* __restrict__ hg1,  // packed [k/4][b] float4
    unsigned* __restrict__ bar,        // [0]=cnt, [32]=gen (separate lines)
    float* __restrict__ out)
{
    __shared__ float4 h4[(HDD / 4) * BB];   // 128 KB: h4[q*64 + b] = h[4q..4q+3][b]
    __shared__ float gv[14 * BB];           // gv[(gate*2+jl)*64 + b]

    const int tid = threadIdx.x;
    const int b   = tid & 63;
    const int wid = __builtin_amdgcn_readfirstlane(tid >> 6);
    const int wg  = blockIdx.x;
    const int jl  = wid & 1;
    const int j   = 2 * wg + jl;
    const bool gatesHi = (wid >= 2);
    const int g0 = gatesHi ? 4 : 0;
    const int nS = gatesHi ? 3 : 4;
    const bool isLamb = (wid == 2) && (wg < KD);

    int crow[4];
    const float4* wrow[4];
#pragma unroll
    for (int s = 0; s < 4; ++s) {
        int g = g0 + ((s < nS) ? s : 0);    // dup for unused slot
        crow[s] = g * HDD + j;
        wrow[s] = (const float4*)(Wvt + (size_t)crow[s] * HDD);
    }
    if (isLamb) wrow[3] = (const float4*)(Wlt + (size_t)wg * HDD);

    const float4* hbr[2] = { (const float4*)hg0, (const float4*)hg1 };
    float*        hbw[2] = { hg0, hg1 };

    float ct = 0.0f, cb = 0.0f;
    unsigned* cnt = bar;
    unsigned* gen = bar + 32;

    for (int t = 0; t <= NE; ++t) {
        // ---- stage h(t-1) into LDS (straight packed copy) ----
        const float4* hin = hbr[t & 1];
#pragma unroll
        for (int i = 0; i < 32; ++i) {
            h4[tid + i * 256] = hin[tid + i * 256];
        }
        __syncthreads();

        // ---- matvec: 4 rows per wave over full K ----
        float acc0 = 0.f, acc1 = 0.f, acc2 = 0.f, acc3 = 0.f;
#pragma unroll 4
        for (int q = 0; q < HDD / 4; ++q) {
            float4 h  = h4[q * 64 + b];
            float4 w0 = wrow[0][q];
            float4 w1 = wrow[1][q];
            float4 w2 = wrow[2][q];
            float4 w3 = wrow[3][q];
            acc0 += h.x * w0.x + h.y * w0.y + h.z * w0.z + h.w * w0.w;
            acc1 += h.x * w1.x + h.y * w1.y + h.z * w1.z + h.w * w1.w;
            acc2 += h.x * w2.x + h.y * w2.y + h.z * w2.z + h.w * w2.w;
            acc3 += h.x * w3.x + h.y * w3.y + h.z * w3.z + h.w * w3.w;
        }

        // ---- gate pre-activations -> LDS ----
        if (t < NE) {
            int mk = marks_t[t * BB + b];
            float accs[4] = {acc0, acc1, acc2, acc3};
#pragma unroll
            for (int s = 0; s < 4; ++s) {
                if (s < nS) {
                    int c = crow[s];
                    float a = accs[s] + bU[c] + bV[c] + Wut[(size_t)c * KD + mk];
                    gv[((g0 + s) * 2 + jl) * BB + b] = a;
                }
            }
        }

        // ---- lamb(t-1) from staged h (pipelined) ----
        if (isLamb && t >= 1) {
            float lt = acc3 + blamb[wg];
            float sc = scale[wg];
            float s  = lt / sc;
            float sp = (s > 20.0f) ? s : log1pf(expf(s));
            out[LAMB_OFF + ((size_t)b * NE + (t - 1)) * KD + wg] = sc * sp;
        }
        __syncthreads();

        // ---- state epilogue on waves 0,1 ----
        if (t < NE && wid < 2) {
            float gi  = gv[(0 * 2 + jl) * BB + b], gf  = gv[(1 * 2 + jl) * BB + b];
            float gib = gv[(2 * 2 + jl) * BB + b], gfb = gv[(3 * 2 + jl) * BB + b];
            float gz  = gv[(4 * 2 + jl) * BB + b], go  = gv[(5 * 2 + jl) * BB + b];
            float gd  = gv[(6 * 2 + jl) * BB + b];

            float iv  = sigf(gi),  fv  = sigf(gf);
            float ibv = sigf(gib), fbv = sigf(gfb);
            float zv  = 2.0f * sigf(gz);
            float ov  = sigf(go);
            float dv  = (gd > 0.0f) ? gd : 0.01f * gd;

            float clow = fv * ct + iv * zv;
            float cbn  = fbv * cb + ibv * zv;
            float dt   = times_t[(t + 1) * BB + b] - times_t[t * BB + b];
            float ctn  = cbn + (clow - cbn) * expf(dt * dv);
            float th   = 2.0f * sigf(2.0f * ctn) - 1.0f;
            float hn   = ov * th;
            ct = ctn; cb = cbn;

            // packed h write: element (q=j>>2, b, comp=j&3)
            hbw[(t + 1) & 1][((j >> 2) * 64 + b) * 4 + (j & 3)] = hn;

            size_t ob = ((size_t)b * NE + t) * HDD + j;
            out[CLOW_OFF  + ob] = clow;
            out[CBAR_OFF  + ob] = cbn;
            out[DELTA_OFF + ob] = dv;
            out[OGATE_OFF + ob] = ov;
        }

        grid_barrier(cnt, gen, gridDim.x);
    }
}

// ---------------- launcher ----------------

extern "C" void kernel_launch(void* const* d_in, const int* in_sizes, int n_in,
                              void* d_out, int out_size, void* d_ws, size_t ws_size,
                              hipStream_t stream)
{
    const float* seq    = (const float*)d_in[0];
    const float* times  = (const float*)d_in[1];
    const float* W_U    = (const float*)d_in[2];
    const float* b_U    = (const float*)d_in[3];
    const float* W_V    = (const float*)d_in[4];
    const float* b_V    = (const float*)d_in[5];
    const float* W_lamb = (const float*)d_in[6];
    const float* b_lamb = (const float*)d_in[7];
    const float* scale  = (const float*)d_in[8];
    float* out = (float*)d_out;

    float* ws      = (float*)d_ws;
    float* Wvt     = ws;                         // 3584*512
    float* Wut     = Wvt + (size_t)NC * HDD;     // 3584*128
    float* Wlt     = Wut + (size_t)NC * KD;      // 128*512
    float* h0      = Wlt + (size_t)KD * HDD;     // 512*64 (packed)
    float* h1      = h0 + HDD * BB;              // 512*64
    float* times_t = h1 + HDD * BB;              // 513*64
    unsigned* bar  = (unsigned*)(times_t + (NE + 1) * BB);   // 64 dwords
    int* marks_t   = (int*)(bar + 64);           // 512*64 ints

    // zero h0 (t=0 state) and barrier counters
    hipMemsetAsync(h0, 0, (size_t)HDD * BB * sizeof(float), stream);
    hipMemsetAsync(bar, 0, 64 * sizeof(unsigned), stream);

    marks_k<<<BB * NE, KD, 0, stream>>>(seq, marks_t);
    transpose_k<<<dim3(NC / 32, HDD / 32), 256, 0, stream>>>(W_V, Wvt, HDD, NC);      // -> [3584][512]
    transpose_k<<<dim3(NC / 32, KD / 32),  256, 0, stream>>>(W_U, Wut, KD, NC);       // -> [3584][128]
    transpose_k<<<dim3(KD / 32, HDD / 32), 256, 0, stream>>>(W_lamb, Wlt, HDD, KD);   // -> [128][512]
    transpose_k<<<dim3((NE + 1 + 31) / 32, BB / 32), 256, 0, stream>>>(times, times_t, BB, NE + 1); // -> [513][64]

    void* args[] = { (void*)&Wvt, (void*)&Wut, (void*)&Wlt, (void*)&b_U, (void*)&b_V,
                     (void*)&b_lamb, (void*)&scale, (void*)&times_t, (void*)&marks_t,
                     (void*)&h0, (void*)&h1, (void*)&bar, (void*)&out };
    hipLaunchCooperativeKernel((const void*)ctlstm_persist, dim3(256), dim3(256),
                               args, 0, stream);
}